// Round 7
// baseline (291.763 us; speedup 1.0000x reference)
//
#include <hip/hip_runtime.h>

#define BB 16      // batch
#define CC 64      // channels (Cin = Cout = 64)
#define HH 128
#define WW 128
#define MM 67      // modes per axis
#define MODES (MM*MM)   // 4489
#define MC 32      // mode chunk for mix
#define NCHUNK 141 // ceil(4489/32)

typedef float f4 __attribute__((ext_vector_type(4)));

__constant__ float DEC_LO[8] = {-0.010597401784997278f, 0.032883011666982945f, 0.030841381835986965f,
                                -0.18703481171888114f, -0.02798376941698385f, 0.6308807679295904f,
                                0.7148465705525415f, 0.23037781330885523f};
__constant__ float DEC_HI[8] = {-0.23037781330885523f, 0.7148465705525415f, -0.6308807679295904f,
                                -0.02798376941698385f, 0.18703481171888114f, 0.030841381835986965f,
                                -0.032883011666982945f, -0.010597401784997278f};

// ---------------- analysis along W: x (B,C,H,W) -> t1 (B,C,2,H,67) ----------------
__global__ __launch_bounds__(256) void dwt_w(const float* __restrict__ x, float* __restrict__ t1) {
    __shared__ float row[8][128];
    const int bc = blockIdx.x;           // 0..1023
    const int h0 = blockIdx.y * 8;       // 0..120
    const int t  = threadIdx.x;
    {
        int r = t >> 5, c = (t & 31) << 2;
        const float4 v = *(const float4*)&x[((size_t)bc * HH + h0 + r) * WW + c];
        row[r][c] = v.x; row[r][c+1] = v.y; row[r][c+2] = v.z; row[r][c+3] = v.w;
    }
    __syncthreads();
    for (int oidx = t; oidx < 8 * 2 * MM; oidx += 256) {
        int wo = oidx % MM;
        int f  = (oidx / MM) & 1;
        int r  = oidx / (2 * MM);
        const float* flt = f ? DEC_HI : DEC_LO;
        float acc = 0.f;
        int base = 2 * wo - 6;
        #pragma unroll
        for (int k = 0; k < 8; ++k) {
            int i = base + k;
            i = (i < 0) ? (-i - 1) : i;
            i = (i >= WW) ? (2 * WW - 1 - i) : i;
            acc += row[r][i] * flt[7 - k];
        }
        t1[(((size_t)bc * 2 + f) * HH + h0 + r) * MM + wo] = acc;
    }
}

// ---------------- analysis along H: t1 -> coeff (B,C,4,67,67), band = fw*2+fh ------
__global__ __launch_bounds__(256) void dwt_h(const float* __restrict__ t1, float* __restrict__ cf) {
    const int NH2 = (MM + 1) / 2;  // 34 ho-pairs
    int idx = blockIdx.x * 256 + threadIdx.x;
    const int N = BB * CC * 2 * NH2 * MM;
    if (idx >= N) return;
    int wo = idx % MM;
    int hp = (idx / MM) % NH2;
    int fw = (idx / (MM * NH2)) % 2;
    int bc = idx / (MM * NH2 * 2);
    const float* src = t1 + ((size_t)(bc * 2 + fw) * HH) * MM + wo;
    float rv[10];
    #pragma unroll
    for (int k = 0; k < 10; ++k) {
        int i = 4 * hp - 6 + k;
        i = (i < 0) ? (-i - 1) : i;
        i = (i >= HH) ? (2 * HH - 1 - i) : i;
        rv[k] = src[(size_t)i * MM];
    }
    float lo0 = 0.f, hi0 = 0.f, lo1 = 0.f, hi1 = 0.f;
    #pragma unroll
    for (int k = 0; k < 8; ++k) {
        lo0 += rv[k]     * DEC_LO[7 - k];
        hi0 += rv[k]     * DEC_HI[7 - k];
        lo1 += rv[k + 2] * DEC_LO[7 - k];
        hi1 += rv[k + 2] * DEC_HI[7 - k];
    }
    int ho0 = 2 * hp, ho1 = 2 * hp + 1;
    size_t b0 = (size_t)(bc * 4 + fw * 2 + 0) * MM;
    size_t b1 = (size_t)(bc * 4 + fw * 2 + 1) * MM;
    cf[(b0 + ho0) * MM + wo] = lo0;
    cf[(b1 + ho0) * MM + wo] = hi0;
    if (ho1 < MM) {
        cf[(b0 + ho1) * MM + wo] = lo1;
        cf[(b1 + ho1) * MM + wo] = hi1;
    }
}

// ---------------- per-mode channel mix ----------------
// out[b,o,band,m] = sum_i cf[b,i,band,m] * w_band[i,o,m]
// Block = (band, 32-mode chunk), ALL b / ALL i / ALL o => zero-redundancy HBM fetch.
// coeff tile (16b x 64i x 32m = 128 KB) in LDS.
// Wave = 4 batches (b-quad); thread = (o-slot of 8 o) x (4 modes).
//   => each ds_read_b128 feeds 32 FMAs; DS instrs per block cut 4x vs o-split.
//   Weight chunk re-read by all 4 waves (L1/L2 absorbs; HBM still once);
//   __syncthreads every 16 i bounds wave drift for L1 reuse.
__global__ __launch_bounds__(256, 1) void mix_k(const float* __restrict__ cf,
                                                const float* __restrict__ w1,
                                                const float* __restrict__ w2,
                                                const float* __restrict__ w3,
                                                const float* __restrict__ w4,
                                                float* __restrict__ out) {
    __shared__ float sc[BB][CC][MC];   // [b][i][m] 128 KB
    // --- bijective XCD swizzle over NWG = 141*4 = 564 = 8*70 + 4 ---
    int flat = blockIdx.y * NCHUNK + blockIdx.x;
    {
        const int q = 564 / 8, r = 564 % 8;          // 70, 4
        int xcd = flat & 7, j = flat >> 3;
        flat = (xcd < r ? xcd * (q + 1) : r * (q + 1) + (xcd - r) * q) + j;
    }
    const int band = flat / NCHUNK;
    const int m0   = min((flat % NCHUNK) * MC, MODES - MC);  // last chunks overlap (identical values)
    const int tid  = threadIdx.x;
    const float* w = (band == 0) ? w1 : (band == 1) ? w2 : (band == 2) ? w3 : w4;

    // ---- stage coeff tile: 1024 rows (b*64+i) x 32 floats ----
    {
        const int c = tid & 7, r0 = tid >> 3;        // 8 threads/row, r0 in [0,32)
        #pragma unroll
        for (int p = 0; p < 32; ++p) {
            int r = r0 + (p << 5);                   // 0..1023
            f4 v = *(const f4*)(cf + ((size_t)(r * 4) + band) * MODES + m0 + c * 4);
            *(f4*)&sc[r >> 6][r & 63][c * 4] = v;
        }
    }
    __syncthreads();

    const int lane = tid & 63, wv = tid >> 6;
    const int b0  = wv * 4;                 // wave's batch quad
    const int os  = (lane >> 3) * 8;        // first o of this thread's 8 consecutive o
    const int mc4 = (lane & 7) * 4;         // mode sub-offset
    const size_t IST = (size_t)CC * MODES;
    const float* wp = w + (size_t)os * MODES + m0 + mc4;   // + k*MODES per o, + i*IST per i

    f4 acc[4][8];
    #pragma unroll
    for (int j = 0; j < 4; ++j)
        #pragma unroll
        for (int k = 0; k < 8; ++k) acc[j][k] = (f4)(0.f);

    f4 wa[8], wb[8];
    #pragma unroll
    for (int k = 0; k < 8; ++k) wa[k] = *(const f4*)(wp + (size_t)k * MODES);

    #pragma unroll 1
    for (int i = 0; i < CC; i += 2) {
        if (i == 16 || i == 32 || i == 48) __syncthreads();   // bound wave drift for L1 weight reuse
        // prefetch weights for i+1
        #pragma unroll
        for (int k = 0; k < 8; ++k)
            wb[k] = *(const f4*)(wp + (size_t)k * MODES + (size_t)(i + 1) * IST);
        {
            f4 s0 = *(const f4*)&sc[b0 + 0][i][mc4];
            f4 s1 = *(const f4*)&sc[b0 + 1][i][mc4];
            f4 s2 = *(const f4*)&sc[b0 + 2][i][mc4];
            f4 s3 = *(const f4*)&sc[b0 + 3][i][mc4];
            #pragma unroll
            for (int k = 0; k < 8; ++k) {
                acc[0][k] += s0 * wa[k];
                acc[1][k] += s1 * wa[k];
                acc[2][k] += s2 * wa[k];
                acc[3][k] += s3 * wa[k];
            }
        }
        // prefetch weights for i+2
        if (i + 2 < CC) {
            #pragma unroll
            for (int k = 0; k < 8; ++k)
                wa[k] = *(const f4*)(wp + (size_t)k * MODES + (size_t)(i + 2) * IST);
        }
        {
            f4 s0 = *(const f4*)&sc[b0 + 0][i + 1][mc4];
            f4 s1 = *(const f4*)&sc[b0 + 1][i + 1][mc4];
            f4 s2 = *(const f4*)&sc[b0 + 2][i + 1][mc4];
            f4 s3 = *(const f4*)&sc[b0 + 3][i + 1][mc4];
            #pragma unroll
            for (int k = 0; k < 8; ++k) {
                acc[0][k] += s0 * wb[k];
                acc[1][k] += s1 * wb[k];
                acc[2][k] += s2 * wb[k];
                acc[3][k] += s3 * wb[k];
            }
        }
    }

    #pragma unroll
    for (int j = 0; j < 4; ++j)
        #pragma unroll
        for (int k = 0; k < 8; ++k)
            *(f4*)&out[((size_t)(((b0 + j) * CC + os + k) * 4) + band) * MODES + m0 + mc4] = acc[j][k];
}

// ---------------- synthesis along H: mixed (B,C,4,67,67) -> u1 (B,C,2,128,67) ------
__global__ __launch_bounds__(256) void idwt_h(const float* __restrict__ mx, float* __restrict__ u1) {
    int idx = blockIdx.x * 256 + threadIdx.x;
    const int N = BB * CC * 2 * (HH / 2) * MM;
    if (idx >= N) return;
    int wo = idx % MM;
    int a  = (idx / MM) % (HH / 2);
    int fw = (idx / (MM * (HH / 2))) % 2;
    int bc = idx / (MM * (HH / 2) * 2);
    const float* lo = mx + ((size_t)(bc * 4 + fw * 2) * MODES) + wo;
    const float* hi = lo + MODES;
    float l[4], h4[4];
    #pragma unroll
    for (int q = 0; q < 4; ++q) {
        l[q]  = lo[(size_t)(a + q) * MM];
        h4[q] = hi[(size_t)(a + q) * MM];
    }
    float out0 = 0.f, out1 = 0.f;
    #pragma unroll
    for (int q = 0; q < 4; ++q) {
        out0 += l[q] * DEC_LO[2 * q + 1] + h4[q] * DEC_HI[2 * q + 1];  // h = 2a
        out1 += l[q] * DEC_LO[2 * q]     + h4[q] * DEC_HI[2 * q];      // h = 2a+1
    }
    size_t base = ((size_t)(bc * 2 + fw) * HH + 2 * a) * MM + wo;
    u1[base]      = out0;
    u1[base + MM] = out1;
}

// ---------------- synthesis along W: u1 -> out (B,C,128,128) ----------------
__global__ __launch_bounds__(256) void idwt_w(const float* __restrict__ u1, float* __restrict__ out) {
    int idx = blockIdx.x * 256 + threadIdx.x;
    const int N = BB * CC * HH * (WW / 2);
    if (idx >= N) return;
    int a  = idx % (WW / 2);
    int h  = (idx / (WW / 2)) % HH;
    int bc = idx / ((WW / 2) * HH);
    const float* lo = u1 + (size_t)(bc * 2) * HH * MM + (size_t)h * MM;
    const float* hi = lo + (size_t)HH * MM;
    float l[4], h4[4];
    #pragma unroll
    for (int q = 0; q < 4; ++q) {
        l[q]  = lo[a + q];
        h4[q] = hi[a + q];
    }
    float out0 = 0.f, out1 = 0.f;
    #pragma unroll
    for (int q = 0; q < 4; ++q) {
        out0 += l[q] * DEC_LO[2 * q + 1] + h4[q] * DEC_HI[2 * q + 1];  // n = 2a
        out1 += l[q] * DEC_LO[2 * q]     + h4[q] * DEC_HI[2 * q];      // n = 2a+1
    }
    float2 r = make_float2(out0, out1);
    *(float2*)&out[((size_t)bc * HH + h) * WW + 2 * a] = r;
}

extern "C" void kernel_launch(void* const* d_in, const int* in_sizes, int n_in,
                              void* d_out, int out_size, void* d_ws, size_t ws_size,
                              hipStream_t stream) {
    const float* x  = (const float*)d_in[0];
    const float* w1 = (const float*)d_in[1];
    const float* w2 = (const float*)d_in[2];
    const float* w3 = (const float*)d_in[3];
    const float* w4 = (const float*)d_in[4];
    float* out = (float*)d_out;

    const size_t COEFF_FLTS = (size_t)BB * CC * 4 * MODES;
    float* buf1 = (float*)d_ws;
    float* buf2 = buf1 + COEFF_FLTS;

    // 1) DWT along W: x -> buf1 (t1)
    {
        dim3 grid(BB * CC, HH / 8);
        dwt_w<<<grid, 256, 0, stream>>>(x, buf1);
    }
    // 2) DWT along H: buf1 -> buf2 (coeff)
    {
        int N = BB * CC * 2 * ((MM + 1) / 2) * MM;
        dwt_h<<<(N + 255) / 256, 256, 0, stream>>>(buf1, buf2);
    }
    // 3) per-mode channel mixing: buf2 -> buf1 (mixed)
    {
        dim3 grid(NCHUNK, 4);   // (141 mode-chunks, 4 bands)
        mix_k<<<grid, 256, 0, stream>>>(buf2, w1, w2, w3, w4, buf1);
    }
    // 4) inverse DWT along H: buf1 -> buf2 (u1)
    {
        int N = BB * CC * 2 * (HH / 2) * MM;
        idwt_h<<<(N + 255) / 256, 256, 0, stream>>>(buf1, buf2);
    }
    // 5) inverse DWT along W: buf2 -> d_out
    {
        int N = BB * CC * HH * (WW / 2);
        idwt_w<<<(N + 255) / 256, 256, 0, stream>>>(buf2, out);
    }
}

// Round 8
// 286.837 us; speedup vs baseline: 1.0172x; 1.0172x over previous
//
#include <hip/hip_runtime.h>

#define BB 16      // batch
#define CC 64      // channels (Cin = Cout = 64)
#define HH 128
#define WW 128
#define MM 67      // modes per axis
#define MODES (MM*MM)   // 4489
#define MC 32      // mode chunk for mix
#define NCHUNK 141 // ceil(4489/32)

typedef float f4 __attribute__((ext_vector_type(4)));

__constant__ float DEC_LO[8] = {-0.010597401784997278f, 0.032883011666982945f, 0.030841381835986965f,
                                -0.18703481171888114f, -0.02798376941698385f, 0.6308807679295904f,
                                0.7148465705525415f, 0.23037781330885523f};
__constant__ float DEC_HI[8] = {-0.23037781330885523f, 0.7148465705525415f, -0.6308807679295904f,
                                -0.02798376941698385f, 0.18703481171888114f, 0.030841381835986965f,
                                -0.032883011666982945f, -0.010597401784997278f};

// ---------------- analysis along W: x (B,C,H,W) -> t1 (B,C,2,H,67) ----------------
__global__ __launch_bounds__(256) void dwt_w(const float* __restrict__ x, float* __restrict__ t1) {
    __shared__ float row[8][128];
    const int bc = blockIdx.x;           // 0..1023
    const int h0 = blockIdx.y * 8;       // 0..120
    const int t  = threadIdx.x;
    {
        int r = t >> 5, c = (t & 31) << 2;
        const float4 v = *(const float4*)&x[((size_t)bc * HH + h0 + r) * WW + c];
        row[r][c] = v.x; row[r][c+1] = v.y; row[r][c+2] = v.z; row[r][c+3] = v.w;
    }
    __syncthreads();
    for (int oidx = t; oidx < 8 * 2 * MM; oidx += 256) {
        int wo = oidx % MM;
        int f  = (oidx / MM) & 1;
        int r  = oidx / (2 * MM);
        const float* flt = f ? DEC_HI : DEC_LO;
        float acc = 0.f;
        int base = 2 * wo - 6;
        #pragma unroll
        for (int k = 0; k < 8; ++k) {
            int i = base + k;
            i = (i < 0) ? (-i - 1) : i;
            i = (i >= WW) ? (2 * WW - 1 - i) : i;
            acc += row[r][i] * flt[7 - k];
        }
        t1[(((size_t)bc * 2 + f) * HH + h0 + r) * MM + wo] = acc;
    }
}

// ---------------- analysis along H: t1 -> coeff (B,C,4,67,67), band = fw*2+fh ------
__global__ __launch_bounds__(256) void dwt_h(const float* __restrict__ t1, float* __restrict__ cf) {
    const int NH2 = (MM + 1) / 2;  // 34 ho-pairs
    int idx = blockIdx.x * 256 + threadIdx.x;
    const int N = BB * CC * 2 * NH2 * MM;
    if (idx >= N) return;
    int wo = idx % MM;
    int hp = (idx / MM) % NH2;
    int fw = (idx / (MM * NH2)) % 2;
    int bc = idx / (MM * NH2 * 2);
    const float* src = t1 + ((size_t)(bc * 2 + fw) * HH) * MM + wo;
    float rv[10];
    #pragma unroll
    for (int k = 0; k < 10; ++k) {
        int i = 4 * hp - 6 + k;
        i = (i < 0) ? (-i - 1) : i;
        i = (i >= HH) ? (2 * HH - 1 - i) : i;
        rv[k] = src[(size_t)i * MM];
    }
    float lo0 = 0.f, hi0 = 0.f, lo1 = 0.f, hi1 = 0.f;
    #pragma unroll
    for (int k = 0; k < 8; ++k) {
        lo0 += rv[k]     * DEC_LO[7 - k];
        hi0 += rv[k]     * DEC_HI[7 - k];
        lo1 += rv[k + 2] * DEC_LO[7 - k];
        hi1 += rv[k + 2] * DEC_HI[7 - k];
    }
    int ho0 = 2 * hp, ho1 = 2 * hp + 1;
    size_t b0 = (size_t)(bc * 4 + fw * 2 + 0) * MM;
    size_t b1 = (size_t)(bc * 4 + fw * 2 + 1) * MM;
    cf[(b0 + ho0) * MM + wo] = lo0;
    cf[(b1 + ho0) * MM + wo] = hi0;
    if (ho1 < MM) {
        cf[(b0 + ho1) * MM + wo] = lo1;
        cf[(b1 + ho1) * MM + wo] = hi1;
    }
}

// ---------------- per-mode channel mix ----------------
// out[b,o,band,m] = sum_i cf[b,i,band,m] * w_band[i,o,m]
// Block = (band, 32-mode chunk), ALL b / ALL i / ALL o => zero-redundancy HBM fetch.
// coeff tile (16b x 64i x 32m = 128 KB) in LDS.
// 512 threads = 8 waves = 2 waves/SIMD (TLP hides weight-load latency; the
// 1-wave/SIMD rounds 5-7 were latency-serialized at 15% VALUBusy).
// Thread = 4 batches x 4 o x 4 modes: per wave per i = 4 VMEM + 4 DS + 64 FMA
// (balanced pipes; weight rows re-read 4x through L1/L2 only, HBM once).
__global__ __launch_bounds__(512, 2) void mix_k(const float* __restrict__ cf,
                                                const float* __restrict__ w1,
                                                const float* __restrict__ w2,
                                                const float* __restrict__ w3,
                                                const float* __restrict__ w4,
                                                float* __restrict__ out) {
    __shared__ float sc[BB][CC][MC];   // [b][i][m] 128 KB
    // --- bijective XCD swizzle over NWG = 141*4 = 564 = 8*70 + 4 ---
    int flat = blockIdx.y * NCHUNK + blockIdx.x;
    {
        const int q = 564 / 8, r = 564 % 8;          // 70, 4
        int xcd = flat & 7, j = flat >> 3;
        flat = (xcd < r ? xcd * (q + 1) : r * (q + 1) + (xcd - r) * q) + j;
    }
    const int band = flat / NCHUNK;
    const int m0   = min((flat % NCHUNK) * MC, MODES - MC);  // last chunks overlap (identical values)
    const int tid  = threadIdx.x;
    const float* w = (band == 0) ? w1 : (band == 1) ? w2 : (band == 2) ? w3 : w4;

    // ---- stage coeff tile: 1024 rows (b*64+i) x 32 floats, 512 threads ----
    {
        const int c = tid & 7, r0 = tid >> 3;        // 8 threads/row, r0 in [0,64)
        #pragma unroll
        for (int p = 0; p < 16; ++p) {
            int r = r0 + (p << 6);                   // 0..1023
            f4 v = *(const f4*)(cf + ((size_t)(r * 4) + band) * MODES + m0 + c * 4);
            *(f4*)&sc[r >> 6][r & 63][c * 4] = v;
        }
    }
    __syncthreads();

    const int lane = tid & 63, wv = tid >> 6;
    const int b0  = (wv & 3) * 4;                      // wave's batch quad
    const int os  = (wv >> 2) * 32 + (lane >> 3) * 4;  // first of 4 consecutive o
    const int mc4 = (lane & 7) * 4;                    // mode sub-offset
    const size_t IST = (size_t)CC * MODES;
    const float* wp = w + (size_t)os * MODES + m0 + mc4;   // + k*MODES per o, + i*IST per i

    f4 acc[4][4];   // [b][o]
    #pragma unroll
    for (int j = 0; j < 4; ++j)
        #pragma unroll
        for (int k = 0; k < 4; ++k) acc[j][k] = (f4)(0.f);

    f4 wa0, wa1, wa2, wa3, wb0, wb1, wb2, wb3;
    wa0 = *(const f4*)(wp + 0 * MODES);
    wa1 = *(const f4*)(wp + 1 * MODES);
    wa2 = *(const f4*)(wp + 2 * MODES);
    wa3 = *(const f4*)(wp + 3 * MODES);

    #pragma unroll 1
    for (int i = 0; i < CC; i += 2) {
        // prefetch weights for i+1
        {
            const float* p1 = wp + (size_t)(i + 1) * IST;
            wb0 = *(const f4*)(p1 + 0 * MODES);
            wb1 = *(const f4*)(p1 + 1 * MODES);
            wb2 = *(const f4*)(p1 + 2 * MODES);
            wb3 = *(const f4*)(p1 + 3 * MODES);
        }
        {
            f4 s0 = *(const f4*)&sc[b0 + 0][i][mc4];
            f4 s1 = *(const f4*)&sc[b0 + 1][i][mc4];
            f4 s2 = *(const f4*)&sc[b0 + 2][i][mc4];
            f4 s3 = *(const f4*)&sc[b0 + 3][i][mc4];
            acc[0][0] += s0 * wa0;  acc[0][1] += s0 * wa1;  acc[0][2] += s0 * wa2;  acc[0][3] += s0 * wa3;
            acc[1][0] += s1 * wa0;  acc[1][1] += s1 * wa1;  acc[1][2] += s1 * wa2;  acc[1][3] += s1 * wa3;
            acc[2][0] += s2 * wa0;  acc[2][1] += s2 * wa1;  acc[2][2] += s2 * wa2;  acc[2][3] += s2 * wa3;
            acc[3][0] += s3 * wa0;  acc[3][1] += s3 * wa1;  acc[3][2] += s3 * wa2;  acc[3][3] += s3 * wa3;
        }
        // prefetch weights for i+2
        if (i + 2 < CC) {
            const float* p2 = wp + (size_t)(i + 2) * IST;
            wa0 = *(const f4*)(p2 + 0 * MODES);
            wa1 = *(const f4*)(p2 + 1 * MODES);
            wa2 = *(const f4*)(p2 + 2 * MODES);
            wa3 = *(const f4*)(p2 + 3 * MODES);
        }
        {
            f4 s0 = *(const f4*)&sc[b0 + 0][i + 1][mc4];
            f4 s1 = *(const f4*)&sc[b0 + 1][i + 1][mc4];
            f4 s2 = *(const f4*)&sc[b0 + 2][i + 1][mc4];
            f4 s3 = *(const f4*)&sc[b0 + 3][i + 1][mc4];
            acc[0][0] += s0 * wb0;  acc[0][1] += s0 * wb1;  acc[0][2] += s0 * wb2;  acc[0][3] += s0 * wb3;
            acc[1][0] += s1 * wb0;  acc[1][1] += s1 * wb1;  acc[1][2] += s1 * wb2;  acc[1][3] += s1 * wb3;
            acc[2][0] += s2 * wb0;  acc[2][1] += s2 * wb1;  acc[2][2] += s2 * wb2;  acc[2][3] += s2 * wb3;
            acc[3][0] += s3 * wb0;  acc[3][1] += s3 * wb1;  acc[3][2] += s3 * wb2;  acc[3][3] += s3 * wb3;
        }
    }

    #pragma unroll
    for (int j = 0; j < 4; ++j)
        #pragma unroll
        for (int k = 0; k < 4; ++k)
            *(f4*)&out[((size_t)(((b0 + j) * CC + os + k) * 4) + band) * MODES + m0 + mc4] = acc[j][k];
}

// ---------------- synthesis along H: mixed (B,C,4,67,67) -> u1 (B,C,2,128,67) ------
__global__ __launch_bounds__(256) void idwt_h(const float* __restrict__ mx, float* __restrict__ u1) {
    int idx = blockIdx.x * 256 + threadIdx.x;
    const int N = BB * CC * 2 * (HH / 2) * MM;
    if (idx >= N) return;
    int wo = idx % MM;
    int a  = (idx / MM) % (HH / 2);
    int fw = (idx / (MM * (HH / 2))) % 2;
    int bc = idx / (MM * (HH / 2) * 2);
    const float* lo = mx + ((size_t)(bc * 4 + fw * 2) * MODES) + wo;
    const float* hi = lo + MODES;
    float l[4], h4[4];
    #pragma unroll
    for (int q = 0; q < 4; ++q) {
        l[q]  = lo[(size_t)(a + q) * MM];
        h4[q] = hi[(size_t)(a + q) * MM];
    }
    float out0 = 0.f, out1 = 0.f;
    #pragma unroll
    for (int q = 0; q < 4; ++q) {
        out0 += l[q] * DEC_LO[2 * q + 1] + h4[q] * DEC_HI[2 * q + 1];  // h = 2a
        out1 += l[q] * DEC_LO[2 * q]     + h4[q] * DEC_HI[2 * q];      // h = 2a+1
    }
    size_t base = ((size_t)(bc * 2 + fw) * HH + 2 * a) * MM + wo;
    u1[base]      = out0;
    u1[base + MM] = out1;
}

// ---------------- synthesis along W: u1 -> out (B,C,128,128) ----------------
__global__ __launch_bounds__(256) void idwt_w(const float* __restrict__ u1, float* __restrict__ out) {
    int idx = blockIdx.x * 256 + threadIdx.x;
    const int N = BB * CC * HH * (WW / 2);
    if (idx >= N) return;
    int a  = idx % (WW / 2);
    int h  = (idx / (WW / 2)) % HH;
    int bc = idx / ((WW / 2) * HH);
    const float* lo = u1 + (size_t)(bc * 2) * HH * MM + (size_t)h * MM;
    const float* hi = lo + (size_t)HH * MM;
    float l[4], h4[4];
    #pragma unroll
    for (int q = 0; q < 4; ++q) {
        l[q]  = lo[a + q];
        h4[q] = hi[a + q];
    }
    float out0 = 0.f, out1 = 0.f;
    #pragma unroll
    for (int q = 0; q < 4; ++q) {
        out0 += l[q] * DEC_LO[2 * q + 1] + h4[q] * DEC_HI[2 * q + 1];  // n = 2a
        out1 += l[q] * DEC_LO[2 * q]     + h4[q] * DEC_HI[2 * q];      // n = 2a+1
    }
    float2 r = make_float2(out0, out1);
    *(float2*)&out[((size_t)bc * HH + h) * WW + 2 * a] = r;
}

extern "C" void kernel_launch(void* const* d_in, const int* in_sizes, int n_in,
                              void* d_out, int out_size, void* d_ws, size_t ws_size,
                              hipStream_t stream) {
    const float* x  = (const float*)d_in[0];
    const float* w1 = (const float*)d_in[1];
    const float* w2 = (const float*)d_in[2];
    const float* w3 = (const float*)d_in[3];
    const float* w4 = (const float*)d_in[4];
    float* out = (float*)d_out;

    const size_t COEFF_FLTS = (size_t)BB * CC * 4 * MODES;
    float* buf1 = (float*)d_ws;
    float* buf2 = buf1 + COEFF_FLTS;

    // 1) DWT along W: x -> buf1 (t1)
    {
        dim3 grid(BB * CC, HH / 8);
        dwt_w<<<grid, 256, 0, stream>>>(x, buf1);
    }
    // 2) DWT along H: buf1 -> buf2 (coeff)
    {
        int N = BB * CC * 2 * ((MM + 1) / 2) * MM;
        dwt_h<<<(N + 255) / 256, 256, 0, stream>>>(buf1, buf2);
    }
    // 3) per-mode channel mixing: buf2 -> buf1 (mixed)
    {
        dim3 grid(NCHUNK, 4);   // (141 mode-chunks, 4 bands)
        mix_k<<<grid, 512, 0, stream>>>(buf2, w1, w2, w3, w4, buf1);
    }
    // 4) inverse DWT along H: buf1 -> buf2 (u1)
    {
        int N = BB * CC * 2 * (HH / 2) * MM;
        idwt_h<<<(N + 255) / 256, 256, 0, stream>>>(buf1, buf2);
    }
    // 5) inverse DWT along W: buf2 -> d_out
    {
        int N = BB * CC * HH * (WW / 2);
        idwt_w<<<(N + 255) / 256, 256, 0, stream>>>(buf2, out);
    }
}